// Round 4
// baseline (1209.788 us; speedup 1.0000x reference)
//
#include <hip/hip_runtime.h>
#include <hip/hip_bf16.h>

typedef __attribute__((ext_vector_type(8))) short short8;
typedef __attribute__((ext_vector_type(4))) float f32x4;

__device__ __forceinline__ unsigned short f2bf(float v) {
    __hip_bfloat16 h = __float2bfloat16(v);   // RNE
    return *reinterpret_cast<unsigned short*>(&h);
}
__device__ __forceinline__ float bf2f(unsigned short u) {
    union { unsigned int i; float f; } x;
    x.i = (unsigned int)u << 16;
    return x.f;
}

constexpr int MAXB = 2048;   // max fine buckets (N/64 = 1563 here)

// ---------------------------------------------------------------------------
// MFMA relation GEMM: C[r][n][H] = bf16(A[n][64]) . bf16(W[r][64][H]) for all
// r in one block (A staged once). 256 thr = 4 waves; wave w computes 16 nodes.
// ---------------------------------------------------------------------------
template<int H>   // 64 (layer1) or 32 (layer2)
__global__ __launch_bounds__(256) void gemm_rel_mfma(
    const float* __restrict__ A, const float* __restrict__ W,
    unsigned short* __restrict__ C, int N, int R, int relu)
{
    constexpr int AS = 88;
    __shared__ unsigned short As[64 * AS];   // [node][d]
    __shared__ unsigned short Bs[H * AS];    // [h][d]  (W transposed)
    const int tid = threadIdx.x;
    const int n0 = blockIdx.x * 64;

    #pragma unroll
    for (int i = 0; i < 4; ++i) {
        int lin = tid + i * 256;            // 1024 float4 slots
        int n = lin >> 4;
        int d4 = (lin & 15) * 4;
        int gn = n0 + n;
        float4 v = make_float4(0.f, 0.f, 0.f, 0.f);
        if (gn < N) v = *(const float4*)&A[(size_t)gn * 64 + d4];
        if (relu) {
            v.x = fmaxf(v.x, 0.f); v.y = fmaxf(v.y, 0.f);
            v.z = fmaxf(v.z, 0.f); v.w = fmaxf(v.w, 0.f);
        }
        ushort4 u;
        u.x = f2bf(v.x); u.y = f2bf(v.y); u.z = f2bf(v.z); u.w = f2bf(v.w);
        *(ushort4*)&As[n * AS + d4] = u;
    }

    const int w = tid >> 6, lane = tid & 63;
    const int m = lane & 15, quad = lane >> 4;

    __syncthreads();

    short8 afrag[2];
    afrag[0] = *(const short8*)&As[(w * 16 + m) * AS + 0 * 32 + quad * 8];
    afrag[1] = *(const short8*)&As[(w * 16 + m) * AS + 1 * 32 + quad * 8];

    constexpr int NT = H / 16;
    for (int r = 0; r < R; ++r) {
        __syncthreads();
        #pragma unroll
        for (int i = 0; i < (64 * H) / 256; ++i) {
            int lin = tid + i * 256;
            int d = lin / H;
            int h = lin % H;
            Bs[h * AS + d] = f2bf(W[((size_t)r * 64 + d) * H + h]);
        }
        __syncthreads();

        f32x4 acc[NT];
        #pragma unroll
        for (int nt = 0; nt < NT; ++nt) {
            acc[nt] = (f32x4){0.f, 0.f, 0.f, 0.f};
            #pragma unroll
            for (int kc = 0; kc < 2; ++kc) {
                short8 bfrag = *(const short8*)&Bs[(nt * 16 + m) * AS + kc * 32 + quad * 8];
                acc[nt] = __builtin_amdgcn_mfma_f32_16x16x32_bf16(afrag[kc], bfrag, acc[nt], 0, 0, 0);
            }
        }
        #pragma unroll
        for (int nt = 0; nt < NT; ++nt) {
            int col = nt * 16 + m;
            #pragma unroll
            for (int i = 0; i < 4; ++i) {
                int node = n0 + w * 16 + quad * 4 + i;
                if (node < N)
                    C[((size_t)r * N + node) * H + col] = f2bf(acc[nt][i]);
            }
        }
    }
}

// ---------------------------------------------------------------------------
// fp32 tiled GEMM for the small self-loop terms (C = A.B + bias, opt ReLU(A)).
// ---------------------------------------------------------------------------
template<int MPR>
__global__ __launch_bounds__(256) void gemm_rel(
    const float* __restrict__ A, const float* __restrict__ B,
    const float* __restrict__ bias, float* __restrict__ C,
    int N, int Mtotal, int relu)
{
    __shared__ float As[64][68];
    __shared__ float Bs[64][64];
    const int tid = threadIdx.x;
    const int n0 = blockIdx.x * 64;
    const int mb = blockIdx.y * 64;

    #pragma unroll
    for (int idx = tid; idx < 4096; idx += 256) {
        int n = idx >> 6, d = idx & 63;
        int gn = n0 + n;
        float v = 0.f;
        if (gn < N) v = A[(size_t)gn * 64 + d];
        if (relu) v = fmaxf(v, 0.f);
        As[d][n] = v;
    }
    #pragma unroll
    for (int idx = tid; idx < 4096; idx += 256) {
        int d = idx >> 6, ml = idx & 63;
        int gm = mb + ml;
        float v = 0.f;
        if (gm < Mtotal) {
            int r = gm / MPR, o = gm % MPR;
            v = B[((size_t)r * 64 + d) * MPR + o];
        }
        Bs[d][ml] = v;
    }
    __syncthreads();

    const int tx = tid & 15, ty = tid >> 4;
    float acc[4][4] = {};
    #pragma unroll 8
    for (int d = 0; d < 64; ++d) {
        float4 a4 = *(const float4*)&As[d][tx * 4];
        float4 b4 = *(const float4*)&Bs[d][ty * 4];
        float a[4] = {a4.x, a4.y, a4.z, a4.w};
        float b[4] = {b4.x, b4.y, b4.z, b4.w};
        #pragma unroll
        for (int i = 0; i < 4; ++i)
            #pragma unroll
            for (int j = 0; j < 4; ++j)
                acc[i][j] = fmaf(a[i], b[j], acc[i][j]);
    }

    const int gm0 = mb + ty * 4;
    if (gm0 < Mtotal) {
        const int r = gm0 / MPR, o = gm0 % MPR;
        float4 bv = make_float4(0.f, 0.f, 0.f, 0.f);
        if (bias) bv = make_float4(bias[o], bias[o+1], bias[o+2], bias[o+3]);
        #pragma unroll
        for (int i = 0; i < 4; ++i) {
            int gn = n0 + tx * 4 + i;
            if (gn < N) {
                float4 v = make_float4(acc[i][0] + bv.x, acc[i][1] + bv.y,
                                       acc[i][2] + bv.z, acc[i][3] + bv.w);
                *(float4*)&C[((size_t)r * N + gn) * MPR + o] = v;
            }
        }
    }
}

// ---------------------------------------------------------------------------
// Bucket partition machinery. Bucket = 64 consecutive dst nodes.
// Record: (et*N + src) << 6 | (dst & 63).
// ---------------------------------------------------------------------------
__global__ __launch_bounds__(256) void zero_int(int* __restrict__ p, int n) {
    int i = blockIdx.x * 256 + threadIdx.x;
    if (i < n) p[i] = 0;
}

__global__ __launch_bounds__(256) void fine_hist(
    const int* __restrict__ dst, int* __restrict__ ghist, int E, int B, int CH)
{
    __shared__ int hist[MAXB];
    const int t = threadIdx.x;
    const int e0 = blockIdx.x * CH, e1 = min(E, e0 + CH);
    for (int i = t; i < B; i += 256) hist[i] = 0;
    __syncthreads();
    for (int e = e0 + t; e < e1; e += 256) atomicAdd(&hist[dst[e] >> 6], 1);
    __syncthreads();
    for (int i = t; i < B; i += 256) {
        int h = hist[i];
        if (h) atomicAdd(&ghist[i], h);
    }
}

// One-block exclusive scan over B bucket counts -> bstart[B+1] and cursor[B].
__global__ __launch_bounds__(256) void fine_scan(
    const int* __restrict__ ghist, int* __restrict__ bstart,
    int* __restrict__ cursor, int B, int E)
{
    __shared__ int ts[256];
    const int t = threadIdx.x;
    const int PER = (B + 255) / 256;   // <= 8
    int loc[8];
    int s = 0;
    for (int j = 0; j < PER; ++j) {
        int i = t * PER + j;
        loc[j] = (i < B) ? ghist[i] : 0;
        s += loc[j];
    }
    ts[t] = s;
    __syncthreads();
    for (int off = 1; off < 256; off <<= 1) {
        int x = (t >= off) ? ts[t - off] : 0;
        __syncthreads();
        ts[t] += x;
        __syncthreads();
    }
    int run = ts[t] - s;
    for (int j = 0; j < PER; ++j) {
        int i = t * PER + j;
        if (i < B) { bstart[i] = run; cursor[i] = run; }
        run += loc[j];
    }
    if (t == 255) bstart[B] = E;
}

__global__ __launch_bounds__(256) void partition_fine(
    const int* __restrict__ src, const int* __restrict__ dst,
    const int* __restrict__ et, int* __restrict__ cursor,
    int* __restrict__ rec, int E, int N, int B, int CH)
{
    __shared__ int hist[MAXB];
    __shared__ int base[MAXB];
    __shared__ int cnt[MAXB];
    const int t = threadIdx.x;
    const int e0 = blockIdx.x * CH, e1 = min(E, e0 + CH);

    for (int i = t; i < B; i += 256) hist[i] = 0;
    __syncthreads();
    for (int e = e0 + t; e < e1; e += 256) atomicAdd(&hist[dst[e] >> 6], 1);
    __syncthreads();
    for (int i = t; i < B; i += 256) {
        int h = hist[i];
        base[i] = h ? atomicAdd(&cursor[i], h) : 0;
        cnt[i] = 0;
    }
    __syncthreads();
    for (int e = e0 + t; e < e1; e += 256) {
        int d = dst[e];
        int b = d >> 6;
        int pos = base[b] + atomicAdd(&cnt[b], 1);
        rec[pos] = ((et[e] * N + src[e]) << 6) | (d & 63);
    }
}

// ---------------------------------------------------------------------------
// Bucketed aggregation: one block per 64-dst-node bucket. fp32 LDS accumulator
// tile initialized from out (self-loop result), ds_add_f32 per edge, coalesced
// writeback. No global atomics, no per-node sort.
// ---------------------------------------------------------------------------
template<int F>
__global__ __launch_bounds__(256) void agg_bucket(
    const unsigned short* __restrict__ hW, const int* __restrict__ bstart,
    const int* __restrict__ rec, float* __restrict__ out, int N)
{
    __shared__ float acc[64 * F];
    const int b = blockIdx.x;
    const int n0 = b * 64;
    const int tid = threadIdx.x;
    const int vcount = min(64, N - n0) * F;   // valid floats in this tile

    for (int i = tid; i < vcount; i += 256)
        acc[i] = out[(size_t)n0 * F + i];
    for (int i = vcount + tid; i < 64 * F; i += 256)
        acc[i] = 0.f;
    __syncthreads();

    const int p0 = bstart[b], p1 = bstart[b + 1];
    const int w = tid >> 6, lane = tid & 63;

    if (F == 64) {
        int p = p0 + w;
        for (; p + 4 < p1; p += 8) {
            int r0 = rec[p], r1 = rec[p + 4];
            float v0 = bf2f(hW[(size_t)(r0 >> 6) * 64 + lane]);
            float v1 = bf2f(hW[(size_t)(r1 >> 6) * 64 + lane]);
            atomicAdd(&acc[(r0 & 63) * 64 + lane], v0);
            atomicAdd(&acc[(r1 & 63) * 64 + lane], v1);
        }
        for (; p < p1; p += 4) {
            int r0 = rec[p];
            float v0 = bf2f(hW[(size_t)(r0 >> 6) * 64 + lane]);
            atomicAdd(&acc[(r0 & 63) * 64 + lane], v0);
        }
    } else {
        // F=32: each wave processes 2 edges per step (32 lanes per edge).
        const int half = lane >> 5, f = lane & 31;
        int p = p0 + 2 * w + half;
        for (; p + 8 < p1; p += 16) {
            int r0 = rec[p], r1 = rec[p + 8];
            float v0 = bf2f(hW[(size_t)(r0 >> 6) * 32 + f]);
            float v1 = bf2f(hW[(size_t)(r1 >> 6) * 32 + f]);
            atomicAdd(&acc[(r0 & 63) * 32 + f], v0);
            atomicAdd(&acc[(r1 & 63) * 32 + f], v1);
        }
        for (; p < p1; p += 8) {
            int r0 = rec[p];
            float v0 = bf2f(hW[(size_t)(r0 >> 6) * 32 + f]);
            atomicAdd(&acc[(r0 & 63) * 32 + f], v0);
        }
    }
    __syncthreads();

    for (int i = tid; i < vcount; i += 256)
        out[(size_t)n0 * F + i] = acc[i];
}

extern "C" void kernel_launch(void* const* d_in, const int* in_sizes, int n_in,
                              void* d_out, int out_size, void* d_ws, size_t ws_size,
                              hipStream_t stream)
{
    const float* feat = (const float*)d_in[0];
    const int*   src  = (const int*)d_in[1];
    const int*   dst  = (const int*)d_in[2];
    const int*   et   = (const int*)d_in[3];
    const float* W1   = (const float*)d_in[4];
    const float* Ws1  = (const float*)d_in[5];
    const float* b1   = (const float*)d_in[6];
    const float* W2   = (const float*)d_in[7];
    const float* Ws2  = (const float*)d_in[8];
    const float* b2   = (const float*)d_in[9];
    float* out = (float*)d_out;

    const int N = in_sizes[0] / 64;           // 100000
    const int E = in_sizes[1];                // 1600000
    const int R = in_sizes[4] / (64 * 64);    // 8
    const int B = (N + 63) / 64;              // 1563 fine buckets

    // Workspace layout
    unsigned short* hW = (unsigned short*)d_ws;          // [R][N][64] bf16 (reused [R][N][32])
    float* h1     = (float*)(hW + (size_t)R * N * 64);   // [N][64] fp32
    int*   ghist  = (int*)(h1 + (size_t)N * 64);         // [B]
    int*   bstart = ghist + B;                           // [B+1]
    int*   cursor = bstart + (B + 1);                    // [B]
    int*   rec    = cursor + B;                          // [E]

    const dim3 blk(256);
    const int nblk64 = (N + 63) / 64;
    const int P  = 128;                       // partition blocks
    const int CH = (E + P - 1) / P;           // 12500 edges per block

    // ---- Bucket partition ----
    zero_int<<<(B + 255) / 256, blk, 0, stream>>>(ghist, B);
    fine_hist<<<P, blk, 0, stream>>>(dst, ghist, E, B, CH);
    fine_scan<<<1, blk, 0, stream>>>(ghist, bstart, cursor, B, E);
    partition_fine<<<P, blk, 0, stream>>>(src, dst, et, cursor, rec, E, N, B, CH);

    // ---- Layer 1 ----
    gemm_rel_mfma<64><<<dim3(nblk64), blk, 0, stream>>>(feat, W1, hW, N, R, 0);
    gemm_rel<64><<<dim3(nblk64, 1), blk, 0, stream>>>(feat, Ws1, b1, h1, N, 64, 0);
    agg_bucket<64><<<dim3(B), blk, 0, stream>>>(hW, bstart, rec, h1, N);

    // ---- Layer 2 ---- (ReLU fused into A staging)
    gemm_rel_mfma<32><<<dim3(nblk64), blk, 0, stream>>>(h1, W2, hW, N, R, 1);
    gemm_rel<32><<<dim3(nblk64, 1), blk, 0, stream>>>(h1, Ws2, b2, out, N, 32, 1);
    agg_bucket<32><<<dim3(B), blk, 0, stream>>>(hW, bstart, rec, out, N);
}

// Round 5
// 457.546 us; speedup vs baseline: 2.6441x; 2.6441x over previous
//
#include <hip/hip_runtime.h>
#include <hip/hip_bf16.h>

typedef __attribute__((ext_vector_type(8))) short short8;
typedef __attribute__((ext_vector_type(4))) float f32x4;

__device__ __forceinline__ unsigned short f2bf(float v) {
    __hip_bfloat16 h = __float2bfloat16(v);   // RNE
    return *reinterpret_cast<unsigned short*>(&h);
}
__device__ __forceinline__ float bf2f(unsigned short u) {
    union { unsigned int i; float f; } x;
    x.i = (unsigned int)u << 16;
    return x.f;
}

constexpr int MAXB = 2048;   // max fine buckets (N/64 = 1563 here)

// ---------------------------------------------------------------------------
// MFMA relation GEMM + fused self-loop. For r<R: C[r][n][H] = bf16 GEMM,
// stored bf16. For r==R: Cself[n][H] = A.Wself + bias, stored fp32.
// One block = 64 nodes, A staged once for all 9 matmuls.
// ---------------------------------------------------------------------------
template<int H>   // 64 (layer1) or 32 (layer2)
__global__ __launch_bounds__(256) void gemm_rel_mfma(
    const float* __restrict__ A, const float* __restrict__ W,
    const float* __restrict__ Wself, const float* __restrict__ bias,
    unsigned short* __restrict__ C, float* __restrict__ Cself,
    int N, int R, int relu)
{
    constexpr int AS = 88;
    __shared__ unsigned short As[64 * AS];   // [node][d]
    __shared__ unsigned short Bs[H * AS];    // [h][d]  (weights transposed)
    const int tid = threadIdx.x;
    const int n0 = blockIdx.x * 64;

    // Stage A tile fp32 -> bf16 (optional ReLU).
    #pragma unroll
    for (int i = 0; i < 4; ++i) {
        int lin = tid + i * 256;            // 1024 float4 slots
        int n = lin >> 4;
        int d4 = (lin & 15) * 4;
        int gn = n0 + n;
        float4 v = make_float4(0.f, 0.f, 0.f, 0.f);
        if (gn < N) v = *(const float4*)&A[(size_t)gn * 64 + d4];
        if (relu) {
            v.x = fmaxf(v.x, 0.f); v.y = fmaxf(v.y, 0.f);
            v.z = fmaxf(v.z, 0.f); v.w = fmaxf(v.w, 0.f);
        }
        ushort4 u;
        u.x = f2bf(v.x); u.y = f2bf(v.y); u.z = f2bf(v.z); u.w = f2bf(v.w);
        *(ushort4*)&As[n * AS + d4] = u;
    }

    const int w = tid >> 6, lane = tid & 63;
    const int m = lane & 15, quad = lane >> 4;

    __syncthreads();

    // A fragments, reused across all R+1 matmuls.
    short8 afrag[2];
    afrag[0] = *(const short8*)&As[(w * 16 + m) * AS + 0 * 32 + quad * 8];
    afrag[1] = *(const short8*)&As[(w * 16 + m) * AS + 1 * 32 + quad * 8];

    constexpr int NT = H / 16;
    for (int r = 0; r <= R; ++r) {
        __syncthreads();   // previous iteration's Bs reads done
        const float* Wsrc = (r < R) ? (W + (size_t)r * 64 * H) : Wself;
        #pragma unroll
        for (int i = 0; i < (64 * H) / 256; ++i) {
            int lin = tid + i * 256;
            int d = lin / H;
            int h = lin % H;
            Bs[h * AS + d] = f2bf(Wsrc[(size_t)d * H + h]);
        }
        __syncthreads();

        f32x4 acc[NT];
        #pragma unroll
        for (int nt = 0; nt < NT; ++nt) {
            acc[nt] = (f32x4){0.f, 0.f, 0.f, 0.f};
            #pragma unroll
            for (int kc = 0; kc < 2; ++kc) {
                short8 bfrag = *(const short8*)&Bs[(nt * 16 + m) * AS + kc * 32 + quad * 8];
                acc[nt] = __builtin_amdgcn_mfma_f32_16x16x32_bf16(afrag[kc], bfrag, acc[nt], 0, 0, 0);
            }
        }
        // C/D layout: col = lane&15, row = quad*4 + i.
        if (r < R) {
            #pragma unroll
            for (int nt = 0; nt < NT; ++nt) {
                int col = nt * 16 + m;
                #pragma unroll
                for (int i = 0; i < 4; ++i) {
                    int node = n0 + w * 16 + quad * 4 + i;
                    if (node < N)
                        C[((size_t)r * N + node) * H + col] = f2bf(acc[nt][i]);
                }
            }
        } else {
            #pragma unroll
            for (int nt = 0; nt < NT; ++nt) {
                int col = nt * 16 + m;
                float bv = bias[col];
                #pragma unroll
                for (int i = 0; i < 4; ++i) {
                    int node = n0 + w * 16 + quad * 4 + i;
                    if (node < N)
                        Cself[(size_t)node * H + col] = acc[nt][i] + bv;
                }
            }
        }
    }
}

// ---------------------------------------------------------------------------
// Bucket partition. Bucket = 64 consecutive dst nodes.
// Record: (et*N + src) << 6 | (dst & 63).
// ---------------------------------------------------------------------------
__global__ __launch_bounds__(256) void zero_int(int* __restrict__ p, int n) {
    int i = blockIdx.x * 256 + threadIdx.x;
    if (i < n) p[i] = 0;
}

__global__ __launch_bounds__(256) void fine_hist(
    const int* __restrict__ dst, int* __restrict__ ghist, int E, int B, int CH)
{
    __shared__ int hist[MAXB];
    const int t = threadIdx.x;
    const int e0 = blockIdx.x * CH, e1 = min(E, e0 + CH);
    for (int i = t; i < B; i += 256) hist[i] = 0;
    __syncthreads();
    for (int e = e0 + t; e < e1; e += 256) atomicAdd(&hist[dst[e] >> 6], 1);
    __syncthreads();
    for (int i = t; i < B; i += 256) {
        int h = hist[i];
        if (h) atomicAdd(&ghist[i], h);
    }
}

__global__ __launch_bounds__(256) void fine_scan(
    const int* __restrict__ ghist, int* __restrict__ bstart,
    int* __restrict__ cursor, int B, int E)
{
    __shared__ int ts[256];
    const int t = threadIdx.x;
    const int PER = (B + 255) / 256;   // <= 8
    int loc[8];
    int s = 0;
    for (int j = 0; j < PER; ++j) {
        int i = t * PER + j;
        loc[j] = (i < B) ? ghist[i] : 0;
        s += loc[j];
    }
    ts[t] = s;
    __syncthreads();
    for (int off = 1; off < 256; off <<= 1) {
        int x = (t >= off) ? ts[t - off] : 0;
        __syncthreads();
        ts[t] += x;
        __syncthreads();
    }
    int run = ts[t] - s;
    for (int j = 0; j < PER; ++j) {
        int i = t * PER + j;
        if (i < B) { bstart[i] = run; cursor[i] = run; }
        run += loc[j];
    }
    if (t == 255) bstart[B] = E;
}

__global__ __launch_bounds__(256) void partition_fine(
    const int* __restrict__ src, const int* __restrict__ dst,
    const int* __restrict__ et, int* __restrict__ cursor,
    int* __restrict__ rec, int E, int N, int B, int CH)
{
    __shared__ int hist[MAXB];
    __shared__ int base[MAXB];
    __shared__ int cnt[MAXB];
    const int t = threadIdx.x;
    const int e0 = blockIdx.x * CH, e1 = min(E, e0 + CH);

    for (int i = t; i < B; i += 256) hist[i] = 0;
    __syncthreads();
    for (int e = e0 + t; e < e1; e += 256) atomicAdd(&hist[dst[e] >> 6], 1);
    __syncthreads();
    for (int i = t; i < B; i += 256) {
        int h = hist[i];
        base[i] = h ? atomicAdd(&cursor[i], h) : 0;
        cnt[i] = 0;
    }
    __syncthreads();
    for (int e = e0 + t; e < e1; e += 256) {
        int d = dst[e];
        int b = d >> 6;
        int pos = base[b] + atomicAdd(&cnt[b], 1);
        rec[pos] = ((et[e] * N + src[e]) << 6) | (d & 63);
    }
}

// ---------------------------------------------------------------------------
// Per-bucket counting sort -> per-node CSR (row_ptr + eidx). One block per
// bucket; eidx writes land inside the bucket's contiguous window (L2-local).
// ---------------------------------------------------------------------------
__global__ __launch_bounds__(256) void bucket_sort(
    const int* __restrict__ bstart, const int* __restrict__ rec,
    int* __restrict__ eidx, int* __restrict__ row_ptr, int N, int E)
{
    __shared__ int hist[64];
    __shared__ int excl[64];
    __shared__ int cur[64];
    const int b = blockIdx.x;
    const int tid = threadIdx.x;
    const int p0 = bstart[b], p1 = bstart[b + 1];

    if (tid < 64) hist[tid] = 0;
    __syncthreads();
    for (int p = p0 + tid; p < p1; p += 256)
        atomicAdd(&hist[rec[p] & 63], 1);
    __syncthreads();
    if (tid == 0) {
        int run = 0;
        #pragma unroll
        for (int i = 0; i < 64; ++i) { excl[i] = run; run += hist[i]; }
    }
    __syncthreads();
    if (tid < 64) {
        cur[tid] = excl[tid];
        int n = b * 64 + tid;
        if (n < N) row_ptr[n] = p0 + excl[tid];
    }
    if (b == 0 && tid == 0) row_ptr[N] = E;
    __syncthreads();
    for (int p = p0 + tid; p < p1; p += 256) {
        int rv = rec[p];
        int pos = p0 + atomicAdd(&cur[rv & 63], 1);
        eidx[pos] = rv >> 6;   // et*N + src
    }
}

// ---------------------------------------------------------------------------
// Gather-side aggregation over bf16 hW (no atomics), fp32 register accumulate.
// One F-lane group per dst node.
// ---------------------------------------------------------------------------
template<int F>
__global__ __launch_bounds__(256) void agg_csr(
    const unsigned short* __restrict__ hW, const int* __restrict__ row_ptr,
    const int* __restrict__ eidx, float* __restrict__ out, int N)
{
    constexpr int G = 256 / F;
    const int d = blockIdx.x * G + threadIdx.x / F;
    const int lane = threadIdx.x % F;
    if (d >= N) return;
    const int p1 = row_ptr[d + 1];
    int p = row_ptr[d];
    float acc = 0.f;
    for (; p + 1 < p1; p += 2) {
        int i0 = eidx[p], i1 = eidx[p + 1];
        acc += bf2f(hW[(size_t)i0 * F + lane]);
        acc += bf2f(hW[(size_t)i1 * F + lane]);
    }
    if (p < p1) acc += bf2f(hW[(size_t)eidx[p] * F + lane]);
    out[(size_t)d * F + lane] += acc;
}

extern "C" void kernel_launch(void* const* d_in, const int* in_sizes, int n_in,
                              void* d_out, int out_size, void* d_ws, size_t ws_size,
                              hipStream_t stream)
{
    const float* feat = (const float*)d_in[0];
    const int*   src  = (const int*)d_in[1];
    const int*   dst  = (const int*)d_in[2];
    const int*   et   = (const int*)d_in[3];
    const float* W1   = (const float*)d_in[4];
    const float* Ws1  = (const float*)d_in[5];
    const float* b1   = (const float*)d_in[6];
    const float* W2   = (const float*)d_in[7];
    const float* Ws2  = (const float*)d_in[8];
    const float* b2   = (const float*)d_in[9];
    float* out = (float*)d_out;

    const int N = in_sizes[0] / 64;           // 100000
    const int E = in_sizes[1];                // 1600000
    const int R = in_sizes[4] / (64 * 64);    // 8
    const int B = (N + 63) / 64;              // 1563 fine buckets

    // Workspace layout
    unsigned short* hW = (unsigned short*)d_ws;          // [R][N][64] bf16 (reused [R][N][32])
    float* h1      = (float*)(hW + (size_t)R * N * 64);  // [N][64] fp32
    int*   ghist   = (int*)(h1 + (size_t)N * 64);        // [B]
    int*   bstart  = ghist + B;                          // [B+1]
    int*   cursor  = bstart + (B + 1);                   // [B]
    int*   row_ptr = cursor + B;                         // [N+1]
    int*   rec     = row_ptr + (N + 1);                  // [E]
    int*   eidx    = rec + E;                            // [E]

    const dim3 blk(256);
    const int nblk64 = (N + 63) / 64;
    const int P  = 128;                       // partition blocks
    const int CH = (E + P - 1) / P;           // 12500 edges per block

    // ---- Build per-node CSR via bucket partition + per-bucket sort ----
    zero_int<<<(B + 255) / 256, blk, 0, stream>>>(ghist, B);
    fine_hist<<<P, blk, 0, stream>>>(dst, ghist, E, B, CH);
    fine_scan<<<1, blk, 0, stream>>>(ghist, bstart, cursor, B, E);
    partition_fine<<<P, blk, 0, stream>>>(src, dst, et, cursor, rec, E, N, B, CH);
    bucket_sort<<<B, blk, 0, stream>>>(bstart, rec, eidx, row_ptr, N, E);

    // ---- Layer 1 ---- (hW1 bf16 + self-loop fp32 into h1, fused)
    gemm_rel_mfma<64><<<dim3(nblk64), blk, 0, stream>>>(feat, W1, Ws1, b1, hW, h1, N, R, 0);
    agg_csr<64><<<dim3((N + 3) / 4), blk, 0, stream>>>(hW, row_ptr, eidx, h1, N);

    // ---- Layer 2 ---- (ReLU fused into A staging)
    gemm_rel_mfma<32><<<dim3(nblk64), blk, 0, stream>>>(h1, W2, Ws2, b2, hW, out, N, R, 1);
    agg_csr<32><<<dim3((N + 7) / 8), blk, 0, stream>>>(hW, row_ptr, eidx, out, N);
}

// Round 6
// 415.617 us; speedup vs baseline: 2.9108x; 1.1009x over previous
//
#include <hip/hip_runtime.h>
#include <hip/hip_bf16.h>

typedef __attribute__((ext_vector_type(8))) short short8;
typedef __attribute__((ext_vector_type(4))) float f32x4;

__device__ __forceinline__ unsigned short f2bf(float v) {
    __hip_bfloat16 h = __float2bfloat16(v);   // RNE
    return *reinterpret_cast<unsigned short*>(&h);
}
__device__ __forceinline__ float bf2f(unsigned short u) {
    union { unsigned int i; float f; } x;
    x.i = (unsigned int)u << 16;
    return x.f;
}

constexpr int MAXB = 2048;   // max fine buckets (N/64 = 1563 here)

// ---------------------------------------------------------------------------
// Weight pre-transpose: Wt[(r*H + h)*64 + d] = bf16( r<R ? W[r][d][h]
//                                                        : Wself[d][h] ).
// Makes each MFMA B-fragment 8 contiguous bf16 (one dwordx4, coalesced).
// ---------------------------------------------------------------------------
template<int H>
__global__ __launch_bounds__(256) void transpose_w(
    const float* __restrict__ W, const float* __restrict__ Wself,
    unsigned short* __restrict__ Wt, int R)
{
    int i = blockIdx.x * 256 + threadIdx.x;
    int total = (R + 1) * H * 64;
    if (i >= total) return;
    int d = i & 63;
    int hh = i >> 6;               // r*H + h
    int r = hh / H, h = hh % H;    // H compile-time -> shifts
    float v = (r < R) ? W[((size_t)r * 64 + d) * H + h]
                      : Wself[(size_t)d * H + h];
    Wt[i] = f2bf(v);
}

// ---------------------------------------------------------------------------
// MFMA relation GEMM, barrier-free r-loop. B-fragments loaded directly from
// pre-transposed bf16 weights in global (L2-resident, coalesced dwordx4).
// r<R: bf16 out to C[r][n][H]; r==R: fp32+bias out to Cself (self-loop).
// ---------------------------------------------------------------------------
template<int H>   // 64 (layer1) or 32 (layer2)
__global__ __launch_bounds__(256) void gemm_rel_mfma(
    const float* __restrict__ A, const unsigned short* __restrict__ Wt,
    const float* __restrict__ bias,
    unsigned short* __restrict__ C, float* __restrict__ Cself,
    int N, int R, int relu)
{
    constexpr int AS = 72;   // ushorts/row: 144 B = 36 words = 4 mod 32 -> 2-way (free)
    __shared__ unsigned short As[64 * AS];
    const int tid = threadIdx.x;
    const int n0 = blockIdx.x * 64;

    // Stage A tile fp32 -> bf16 (optional ReLU). Writes contiguous per node row.
    #pragma unroll
    for (int i = 0; i < 4; ++i) {
        int lin = tid + i * 256;            // 1024 float4 slots
        int n = lin >> 4;
        int d4 = (lin & 15) * 4;
        int gn = n0 + n;
        float4 v = make_float4(0.f, 0.f, 0.f, 0.f);
        if (gn < N) v = *(const float4*)&A[(size_t)gn * 64 + d4];
        if (relu) {
            v.x = fmaxf(v.x, 0.f); v.y = fmaxf(v.y, 0.f);
            v.z = fmaxf(v.z, 0.f); v.w = fmaxf(v.w, 0.f);
        }
        ushort4 u;
        u.x = f2bf(v.x); u.y = f2bf(v.y); u.z = f2bf(v.z); u.w = f2bf(v.w);
        *(ushort4*)&As[n * AS + d4] = u;
    }

    const int w = tid >> 6, lane = tid & 63;
    const int m = lane & 15, quad = lane >> 4;

    __syncthreads();   // the only barrier in the kernel

    // A fragments (lane holds A[node=w*16+m][k=quad*8+j]), reused for all r.
    short8 afrag[2];
    afrag[0] = *(const short8*)&As[(w * 16 + m) * AS + 0 * 32 + quad * 8];
    afrag[1] = *(const short8*)&As[(w * 16 + m) * AS + 1 * 32 + quad * 8];

    constexpr int NT = H / 16;
    for (int r = 0; r <= R; ++r) {
        f32x4 acc[NT];
        #pragma unroll
        for (int nt = 0; nt < NT; ++nt) {
            acc[nt] = (f32x4){0.f, 0.f, 0.f, 0.f};
            #pragma unroll
            for (int kc = 0; kc < 2; ++kc) {
                // B-fragment: 8 contiguous bf16 at Wt[r*H + nt*16+m][kc*32+quad*8]
                short8 bfrag = *(const short8*)
                    &Wt[((size_t)(r * H + nt * 16 + m)) * 64 + kc * 32 + quad * 8];
                acc[nt] = __builtin_amdgcn_mfma_f32_16x16x32_bf16(afrag[kc], bfrag, acc[nt], 0, 0, 0);
            }
        }
        // C/D layout: col = lane&15 (+nt*16), row = quad*4 + i.
        if (r < R) {
            #pragma unroll
            for (int nt = 0; nt < NT; ++nt) {
                int col = nt * 16 + m;
                #pragma unroll
                for (int i = 0; i < 4; ++i) {
                    int node = n0 + w * 16 + quad * 4 + i;
                    if (node < N)
                        C[((size_t)r * N + node) * H + col] = f2bf(acc[nt][i]);
                }
            }
        } else {
            #pragma unroll
            for (int nt = 0; nt < NT; ++nt) {
                int col = nt * 16 + m;
                float bv = bias[col];
                #pragma unroll
                for (int i = 0; i < 4; ++i) {
                    int node = n0 + w * 16 + quad * 4 + i;
                    if (node < N)
                        Cself[(size_t)node * H + col] = acc[nt][i] + bv;
                }
            }
        }
    }
}

// ---------------------------------------------------------------------------
// Bucket partition. Bucket = 64 consecutive dst nodes.
// Record: (et*N + src) << 6 | (dst & 63).
// ---------------------------------------------------------------------------
__global__ __launch_bounds__(256) void zero_int(int* __restrict__ p, int n) {
    int i = blockIdx.x * 256 + threadIdx.x;
    if (i < n) p[i] = 0;
}

__global__ __launch_bounds__(256) void fine_hist(
    const int* __restrict__ dst, int* __restrict__ ghist, int E, int B, int CH)
{
    __shared__ int hist[MAXB];
    const int t = threadIdx.x;
    const int e0 = blockIdx.x * CH, e1 = min(E, e0 + CH);
    for (int i = t; i < B; i += 256) hist[i] = 0;
    __syncthreads();
    for (int e = e0 + t; e < e1; e += 256) atomicAdd(&hist[dst[e] >> 6], 1);
    __syncthreads();
    for (int i = t; i < B; i += 256) {
        int h = hist[i];
        if (h) atomicAdd(&ghist[i], h);
    }
}

__global__ __launch_bounds__(256) void fine_scan(
    const int* __restrict__ ghist, int* __restrict__ bstart,
    int* __restrict__ cursor, int B, int E)
{
    __shared__ int ts[256];
    const int t = threadIdx.x;
    const int PER = (B + 255) / 256;   // <= 8
    int loc[8];
    int s = 0;
    for (int j = 0; j < PER; ++j) {
        int i = t * PER + j;
        loc[j] = (i < B) ? ghist[i] : 0;
        s += loc[j];
    }
    ts[t] = s;
    __syncthreads();
    for (int off = 1; off < 256; off <<= 1) {
        int x = (t >= off) ? ts[t - off] : 0;
        __syncthreads();
        ts[t] += x;
        __syncthreads();
    }
    int run = ts[t] - s;
    for (int j = 0; j < PER; ++j) {
        int i = t * PER + j;
        if (i < B) { bstart[i] = run; cursor[i] = run; }
        run += loc[j];
    }
    if (t == 255) bstart[B] = E;
}

__global__ __launch_bounds__(256) void partition_fine(
    const int* __restrict__ src, const int* __restrict__ dst,
    const int* __restrict__ et, int* __restrict__ cursor,
    int* __restrict__ rec, int E, int N, int B, int CH)
{
    __shared__ int hist[MAXB];
    __shared__ int base[MAXB];
    __shared__ int cnt[MAXB];
    const int t = threadIdx.x;
    const int e0 = blockIdx.x * CH, e1 = min(E, e0 + CH);

    for (int i = t; i < B; i += 256) hist[i] = 0;
    __syncthreads();
    for (int e = e0 + t; e < e1; e += 256) atomicAdd(&hist[dst[e] >> 6], 1);
    __syncthreads();
    for (int i = t; i < B; i += 256) {
        int h = hist[i];
        base[i] = h ? atomicAdd(&cursor[i], h) : 0;
        cnt[i] = 0;
    }
    __syncthreads();
    for (int e = e0 + t; e < e1; e += 256) {
        int d = dst[e];
        int b = d >> 6;
        int pos = base[b] + atomicAdd(&cnt[b], 1);
        rec[pos] = ((et[e] * N + src[e]) << 6) | (d & 63);
    }
}

// ---------------------------------------------------------------------------
// Per-bucket counting sort -> per-node CSR (row_ptr + eidx).
// ---------------------------------------------------------------------------
__global__ __launch_bounds__(256) void bucket_sort(
    const int* __restrict__ bstart, const int* __restrict__ rec,
    int* __restrict__ eidx, int* __restrict__ row_ptr, int N, int E)
{
    __shared__ int hist[64];
    __shared__ int excl[64];
    __shared__ int cur[64];
    const int b = blockIdx.x;
    const int tid = threadIdx.x;
    const int p0 = bstart[b], p1 = bstart[b + 1];

    if (tid < 64) hist[tid] = 0;
    __syncthreads();
    for (int p = p0 + tid; p < p1; p += 256)
        atomicAdd(&hist[rec[p] & 63], 1);
    __syncthreads();
    if (tid == 0) {
        int run = 0;
        #pragma unroll
        for (int i = 0; i < 64; ++i) { excl[i] = run; run += hist[i]; }
    }
    __syncthreads();
    if (tid < 64) {
        cur[tid] = excl[tid];
        int n = b * 64 + tid;
        if (n < N) row_ptr[n] = p0 + excl[tid];
    }
    if (b == 0 && tid == 0) row_ptr[N] = E;
    __syncthreads();
    for (int p = p0 + tid; p < p1; p += 256) {
        int rv = rec[p];
        int pos = p0 + atomicAdd(&cur[rv & 63], 1);
        eidx[pos] = rv >> 6;   // et*N + src
    }
}

// ---------------------------------------------------------------------------
// Gather-side aggregation over bf16 hW, fp32 register accumulate, 4-wide
// unroll with 2 accumulators for memory-level parallelism.
// ---------------------------------------------------------------------------
template<int F>
__global__ __launch_bounds__(256) void agg_csr(
    const unsigned short* __restrict__ hW, const int* __restrict__ row_ptr,
    const int* __restrict__ eidx, float* __restrict__ out, int N)
{
    constexpr int G = 256 / F;
    const int d = blockIdx.x * G + threadIdx.x / F;
    const int lane = threadIdx.x % F;
    if (d >= N) return;
    const int p1 = row_ptr[d + 1];
    int p = row_ptr[d];
    float a0 = 0.f, a1 = 0.f;
    for (; p + 3 < p1; p += 4) {
        int i0 = eidx[p], i1 = eidx[p + 1], i2 = eidx[p + 2], i3 = eidx[p + 3];
        a0 += bf2f(hW[(size_t)i0 * F + lane]);
        a1 += bf2f(hW[(size_t)i1 * F + lane]);
        a0 += bf2f(hW[(size_t)i2 * F + lane]);
        a1 += bf2f(hW[(size_t)i3 * F + lane]);
    }
    for (; p < p1; ++p)
        a0 += bf2f(hW[(size_t)eidx[p] * F + lane]);
    out[(size_t)d * F + lane] += a0 + a1;
}

extern "C" void kernel_launch(void* const* d_in, const int* in_sizes, int n_in,
                              void* d_out, int out_size, void* d_ws, size_t ws_size,
                              hipStream_t stream)
{
    const float* feat = (const float*)d_in[0];
    const int*   src  = (const int*)d_in[1];
    const int*   dst  = (const int*)d_in[2];
    const int*   et   = (const int*)d_in[3];
    const float* W1   = (const float*)d_in[4];
    const float* Ws1  = (const float*)d_in[5];
    const float* b1   = (const float*)d_in[6];
    const float* W2   = (const float*)d_in[7];
    const float* Ws2  = (const float*)d_in[8];
    const float* b2   = (const float*)d_in[9];
    float* out = (float*)d_out;

    const int N = in_sizes[0] / 64;           // 100000
    const int E = in_sizes[1];                // 1600000
    const int R = in_sizes[4] / (64 * 64);    // 8
    const int B = (N + 63) / 64;              // 1563 fine buckets

    // Workspace layout
    unsigned short* hW  = (unsigned short*)d_ws;           // [R][N][64] bf16 (reused [R][N][32])
    float* h1      = (float*)(hW + (size_t)R * N * 64);    // [N][64] fp32
    unsigned short* Wt1 = (unsigned short*)(h1 + (size_t)N * 64);  // [(R+1)*64*64]
    unsigned short* Wt2 = Wt1 + (size_t)(R + 1) * 64 * 64;         // [(R+1)*32*64]
    int*   ghist   = (int*)(Wt2 + (size_t)(R + 1) * 32 * 64);      // [B]
    int*   bstart  = ghist + B;                            // [B+1]
    int*   cursor  = bstart + (B + 1);                     // [B]
    int*   row_ptr = cursor + B;                           // [N+1]
    int*   rec     = row_ptr + (N + 1);                    // [E]
    int*   eidx    = rec + E;                              // [E]

    const dim3 blk(256);
    const int nblk64 = (N + 63) / 64;
    const int P  = 128;                       // partition blocks
    const int CH = (E + P - 1) / P;           // 12500 edges per block

    // ---- Weight pre-transpose (bf16, [r][h][d]) ----
    transpose_w<64><<<((R + 1) * 64 * 64 + 255) / 256, blk, 0, stream>>>(W1, Ws1, Wt1, R);
    transpose_w<32><<<((R + 1) * 32 * 64 + 255) / 256, blk, 0, stream>>>(W2, Ws2, Wt2, R);

    // ---- Build per-node CSR via bucket partition + per-bucket sort ----
    zero_int<<<(B + 255) / 256, blk, 0, stream>>>(ghist, B);
    fine_hist<<<P, blk, 0, stream>>>(dst, ghist, E, B, CH);
    fine_scan<<<1, blk, 0, stream>>>(ghist, bstart, cursor, B, E);
    partition_fine<<<P, blk, 0, stream>>>(src, dst, et, cursor, rec, E, N, B, CH);
    bucket_sort<<<B, blk, 0, stream>>>(bstart, rec, eidx, row_ptr, N, E);

    // ---- Layer 1 ---- (hW1 bf16 + self-loop fp32 into h1, fused)
    gemm_rel_mfma<64><<<dim3(nblk64), blk, 0, stream>>>(feat, Wt1, b1, hW, h1, N, R, 0);
    agg_csr<64><<<dim3((N + 3) / 4), blk, 0, stream>>>(hW, row_ptr, eidx, h1, N);

    // ---- Layer 2 ---- (ReLU fused into A staging)
    gemm_rel_mfma<32><<<dim3(nblk64), blk, 0, stream>>>(h1, Wt2, b2, hW, out, N, R, 1);
    agg_csr<32><<<dim3((N + 7) / 8), blk, 0, stream>>>(hW, row_ptr, eidx, out, N);
}